// Round 1
// 91.532 us; speedup vs baseline: 1.0341x; 1.0341x over previous
//
#include <hip/hip_runtime.h>

// TreeCRF inside pass, L=32 channels, perfect binary tree (heap layout).
// parent[i] = em[i] + LSE_j(T[i,j]+left[j]) + LSE_j(T[i,j]+right[j])
//
// R13 = R12 with the per-level log/exp LSE chain replaced by LINEAR-DOMAIN
// propagation. Each node carries V = exp(scores - m) (bf16, max-normalized)
// and a scalar m (f32, in LDS M[]). Parent combine:
//   u_i  = exp(em_i) * (E V_L)_i * (E V_R)_i      (f32, via MFMA + sibling shfl)
//   mu   = max_i u_i ;  V_p = u / mu ;  m_p = m_L + m_R + log(mu)
// Identity: scores_p[i] = m_p + log(V_p[i])  — exactly the old recurrence.
// Per phase this removes 8 v_log + 8 v_exp per lane from the MFMA-dependent
// critical path (replaced by 8 v_exp(em) that depend only on prefetched em,
// one rcp, and one off-path v_log feeding the scalar m accumulator).
// Interfaces unchanged: ws1/ws2/R4/out rows stay log-domain f32 scores.
//
// Launch structure (unchanged from R12):
//  K1: 4096 waves reduce leaves -> width 4096 (block 0 zeroes the ticket).
//  K2: 32 blocks x 4 waves reduce 4096 -> 128; threadfence + atomicAdd ticket;
//      last block runs 128 -> 4 -> 1 to the root.

typedef float f32x4 __attribute__((ext_vector_type(4)));
typedef short s16x8 __attribute__((ext_vector_type(8)));
typedef short s16x4 __attribute__((ext_vector_type(4)));

#define CSTR 40   // C row stride in shorts (80 B: 16B-aligned, <=2-way banks)
#define LDS_WAIT() __asm__ volatile("s_waitcnt lgkmcnt(0)" ::: "memory")

__device__ __forceinline__ short f2bf(float f) {
    unsigned u = __builtin_bit_cast(unsigned, f);
    unsigned r = (u + 0x7fffu + ((u >> 16) & 1u)) >> 16;   // RNE to bf16
    return (short)r;
}

__device__ __forceinline__ float max4(float4 v) {
    return fmaxf(fmaxf(v.x, v.y), fmaxf(v.z, v.w));
}

__device__ __forceinline__ void load_afrag(const float* __restrict__ trans,
                                           int row, int kg, s16x8* a)
{
#pragma unroll
    for (int j = 0; j < 8; ++j)
        (*a)[j] = f2bf(__expf(trans[row * 32 + kg * 8 + j]));
}

// One wave reduces NC0 rows -> one f32 output row (log2(NC0) levels), fully
// autonomously. em node at step s: (inW>>s)-1 + sid*(NC0>>s) + p.
template <int NC0>
__device__ __forceinline__ void wave_reduce(
    int lane, const float* rows, const float* __restrict__ em, int inW,
    int sid, s16x8 a0, s16x8 a1, short* C, float* M, float* outrow)
{
    constexpr int STEPS = (NC0 == 32) ? 5 : 2;
    constexpr int NPH = (NC0 == 32) ? 6 : 2;
    const int ql = lane & 15, kg = lane >> 4;
    const int q0 = lane & 31, h = lane >> 5;

    // stage-0 row loads first
    float4 x0 = {0,0,0,0}, x1 = x0, x2 = x0, x3 = x0;
    if (q0 < NC0) {
        const float4* src = (const float4*)(rows + q0 * 32 + h * 16);
        x0 = src[0]; x1 = src[1]; x2 = src[2]; x3 = src[3];
    }

    // prefetch ALL em rows needed by the phases (independent, in-flight)
    float4 pe0[NPH], pe1[NPH];
    {
        int ph = 0;
#pragma unroll
        for (int s = 1; s <= STEPS; ++s) {
            const int nca = NC0 >> (s - 1);
            const int nstr = (nca >= 16) ? (nca >> 4) : 1;
#pragma unroll
            for (int st = 0; st < nstr; ++st, ++ph) {
                int p = (st * 16 + ql) >> 1;
                size_t node = (size_t)((inW >> s) - 1)
                            + (size_t)sid * (NC0 >> s) + p;
                pe0[ph] = *(const float4*)(em + node * 32 + kg * 4);
                pe1[ph] = *(const float4*)(em + node * 32 + 16 + kg * 4);
            }
        }
    }

    // stage 0: V = exp(x - rowmax) -> C, rowmax -> M. (Rowmax normalization
    // kept: intermediate log-domain inputs can have |x| ~ O(100), which must
    // not hit exp() unnormalized.)
    if (q0 < NC0) {
        float mm = fmaxf(fmaxf(max4(x0), max4(x1)),
                         fmaxf(max4(x2), max4(x3)));
        mm = fmaxf(mm, __shfl_xor(mm, 32));       // combine the two halves
        s16x8 w0, w1;
        w0[0] = f2bf(__expf(x0.x - mm)); w0[1] = f2bf(__expf(x0.y - mm));
        w0[2] = f2bf(__expf(x0.z - mm)); w0[3] = f2bf(__expf(x0.w - mm));
        w0[4] = f2bf(__expf(x1.x - mm)); w0[5] = f2bf(__expf(x1.y - mm));
        w0[6] = f2bf(__expf(x1.z - mm)); w0[7] = f2bf(__expf(x1.w - mm));
        w1[0] = f2bf(__expf(x2.x - mm)); w1[1] = f2bf(__expf(x2.y - mm));
        w1[2] = f2bf(__expf(x2.z - mm)); w1[3] = f2bf(__expf(x2.w - mm));
        w1[4] = f2bf(__expf(x3.x - mm)); w1[5] = f2bf(__expf(x3.y - mm));
        w1[6] = f2bf(__expf(x3.z - mm)); w1[7] = f2bf(__expf(x3.w - mm));
        *(s16x8*)(C + q0 * CSTR + h * 16) = w0;
        *(s16x8*)(C + q0 * CSTR + h * 16 + 8) = w1;
        if (h == 0) M[q0] = mm;
    }

    int nc = NC0, ph = 0;
#pragma unroll
    for (int s = 1; s <= STEPS; ++s) {
        const int nstr = (nc >= 16) ? (nc >> 4) : 1;
#pragma unroll
        for (int st = 0; st < nstr; ++st, ++ph) {
            LDS_WAIT();   // drain this wave's DS writes; compiler mem barrier
            int q = st * 16 + ql;
            bool valid = q < nc;
            s16x8 b = *(const s16x8*)(C + q * CSTR + kg * 8);
            f32x4 d0 = {0.f, 0.f, 0.f, 0.f};
            f32x4 d1 = {0.f, 0.f, 0.f, 0.f};
            d0 = __builtin_amdgcn_mfma_f32_16x16x32_bf16(a0, b, d0, 0, 0, 0);
            d1 = __builtin_amdgcn_mfma_f32_16x16x32_bf16(a1, b, d1, 0, 0, 0);
            float mq = M[q];
            float mpair = mq + __shfl_xor(mq, 1);   // m_L + m_R for pair
            int p = q >> 1;
            float4 e0 = pe0[ph], e1 = pe1[ph];
            // exp(em): depends only on prefetched registers, NOT on d ->
            // schedules in parallel with the MFMA (off the critical path).
            float w0[4] = {__expf(e0.x), __expf(e0.y),
                           __expf(e0.z), __expf(e0.w)};
            float w1[4] = {__expf(e1.x), __expf(e1.y),
                           __expf(e1.z), __expf(e1.w)};
            float u0[4], u1[4];
#pragma unroll
            for (int r = 0; r < 4; ++r) {
                // sibling product: identical on both lanes of the pair
                u0[r] = d0[r] * __shfl_xor(d0[r], 1) * w0[r];
                u1[r] = d1[r] * __shfl_xor(d1[r], 1) * w1[r];
            }
            if (s == STEPS) {
                if (ql == 0) {                    // single parent row out
                    float4 o0 = {mpair + __logf(u0[0]), mpair + __logf(u0[1]),
                                 mpair + __logf(u0[2]), mpair + __logf(u0[3])};
                    float4 o1 = {mpair + __logf(u1[0]), mpair + __logf(u1[1]),
                                 mpair + __logf(u1[2]), mpair + __logf(u1[3])};
                    *(float4*)(outrow + kg * 4) = o0;
                    *(float4*)(outrow + 16 + kg * 4) = o1;
                }
            } else {
                // mu = max over the parent's 32 channels (per-ql reduce over
                // kg lanes only — invalid lanes never pollute valid ones)
                float m2 = fmaxf(
                    fmaxf(fmaxf(u0[0], u0[1]), fmaxf(u0[2], u0[3])),
                    fmaxf(fmaxf(u1[0], u1[1]), fmaxf(u1[2], u1[3])));
                m2 = fmaxf(m2, __shfl_xor(m2, 16));
                m2 = fmaxf(m2, __shfl_xor(m2, 32));
                float inv = __fdividef(1.f, m2);   // v_rcp + mul, no trans chain
                if (valid && !(q & 1)) {
                    s16x4 z0, z1;
                    z0[0] = f2bf(u0[0] * inv); z0[1] = f2bf(u0[1] * inv);
                    z0[2] = f2bf(u0[2] * inv); z0[3] = f2bf(u0[3] * inv);
                    z1[0] = f2bf(u1[0] * inv); z1[1] = f2bf(u1[1] * inv);
                    z1[2] = f2bf(u1[2] * inv); z1[3] = f2bf(u1[3] * inv);
                    *(s16x4*)(C + p * CSTR + kg * 4) = z0;
                    *(s16x4*)(C + p * CSTR + 16 + kg * 4) = z1;
                    // off-path: log(mu) feeds only the scalar m accumulator
                    if (kg == 0) M[p] = mpair + __logf(m2);
                }
            }
        }
        nc >>= 1;
    }
}

// K1: 4 waves/block, wave wv reduces 32 leaf rows -> out[sid]. Block 0 also
// zeroes the K2 ticket counter (visible to K2 at kernel boundary).
__global__ __launch_bounds__(256) void treecrf_stage1(
    const float* __restrict__ rows_base, const float* __restrict__ em,
    const float* __restrict__ trans, float* __restrict__ out, int inW,
    int* __restrict__ counter)
{
    __shared__ short C[4 * 32 * CSTR];
    __shared__ float M[4 * 32];
    int t = threadIdx.x, lane = t & 63, wv = t >> 6;
    if (blockIdx.x == 0 && t == 0) *counter = 0;
    int sid = blockIdx.x * 4 + wv;
    s16x8 a0, a1;
    load_afrag(trans, lane & 15, lane >> 4, &a0);
    load_afrag(trans, (lane & 15) + 16, lane >> 4, &a1);
    wave_reduce<32>(lane, rows_base + (size_t)sid * 1024, em, inW, sid,
                    a0, a1, C + wv * 32 * CSTR, M + wv * 32,
                    out + (size_t)sid * 32);
}

// K2: 32 blocks x 4 waves reduce 4096 -> 128 (ws2); ticket; last block runs
// 128 -> 4 (4 waves into LDS) -> barrier -> 4 -> 1 (wave 0) -> root.
__global__ __launch_bounds__(256) void treecrf_stage2(
    const float* __restrict__ ws1, float* __restrict__ ws2,
    const float* __restrict__ em, const float* __restrict__ trans,
    int* __restrict__ counter, float* __restrict__ out_root, int nbm1)
{
    __shared__ short C[4 * 32 * CSTR];
    __shared__ float M[4 * 32];
    __shared__ float R4[4 * 32];
    __shared__ int last_flag;
    int t = threadIdx.x, lane = t & 63, wv = t >> 6;
    int sid = blockIdx.x * 4 + wv;
    s16x8 a0, a1;
    load_afrag(trans, lane & 15, lane >> 4, &a0);
    load_afrag(trans, (lane & 15) + 16, lane >> 4, &a1);
    wave_reduce<32>(lane, ws1 + (size_t)sid * 1024, em, 4096, sid,
                    a0, a1, C + wv * 32 * CSTR, M + wv * 32,
                    ws2 + (size_t)sid * 32);

    if (t == 0) {
        __threadfence();                   // release this block's ws2 rows
        last_flag = (atomicAdd(counter, 1) == nbm1);
    }
    __syncthreads();
    if (!last_flag) return;
    __threadfence();                       // acquire all ws2 rows

    wave_reduce<32>(lane, ws2 + (size_t)wv * 1024, em, 128, wv,
                    a0, a1, C + wv * 32 * CSTR, M + wv * 32, R4 + wv * 32);
    __syncthreads();                       // cross-wave R4 handoff
    if (wv == 0)
        wave_reduce<4>(lane, R4, em, 4, 0, a0, a1, C, M, out_root);
}

extern "C" void kernel_launch(void* const* d_in, const int* in_sizes, int n_in,
                              void* d_out, int out_size, void* d_ws, size_t ws_size,
                              hipStream_t stream)
{
    const float* em = (const float*)d_in[0];
    const float* trans = (const float*)d_in[1];
    int n_nodes = in_sizes[0] / 32;          // 262143
    int n_leaves = (n_nodes + 1) / 2;        // 131072

    float* ws1 = (float*)d_ws;               // 4096 rows
    float* ws2 = ws1 + (size_t)4096 * 32;    // 128 rows
    int* counter = (int*)(ws2 + (size_t)128 * 32);

    // K1: leaves (width 131072) -> width 4096. 4096 waves = 1024 blocks.
    treecrf_stage1<<<dim3(n_leaves / 128), dim3(256), 0, stream>>>(
        em + (size_t)(n_leaves - 1) * 32, em, trans, ws1, n_leaves, counter);
    // K2: width 4096 -> root (last-block-done fuses the tail).
    treecrf_stage2<<<dim3(32), dim3(256), 0, stream>>>(
        ws1, ws2, em, trans, counter, (float*)d_out, 31);
}